// Round 4
// baseline (303.597 us; speedup 1.0000x reference)
//
#include <hip/hip_runtime.h>

// dims
#define BB 2
#define SS 1024
#define HH 8
#define DD 64
#define RR 32
#define KK 128
#define ZLEN 1536
#define HD 512

// tiling
#define MS 256            // s per block (4 stiles)
#define DC 16             // d per block (4 dc chunks)
#define NTC 24            // t-chunks of 16 (window = 256+128 = 384)
#define WROWS 192         // tau in [-32,160), zero-padded outside [0,128)
#define WSEG (WROWS*DC)   // 3072 halves = 6 KB per (h,dc) per array
#define PARTS_FLOATS (256*8*2*64*16)   // 4,194,304 f32 = 16 MiB

typedef _Float16 f16x8 __attribute__((ext_vector_type(8)));
typedef _Float16 f16x2 __attribute__((ext_vector_type(2)));
typedef float    f32x16 __attribute__((ext_vector_type(16)));

// ---- main: C[r][s] = sum_{t,d} z[r,d,t] * (w[d,t-s]*qk[s,d]), MFMA 32x32x16 f16 ----
// block = (b,h,stile,dc), 1024 thr = 16 waves: wave = (ssub 0..7, parity half).
// 4-deep zbuf ring, write-lead 2, global-load lead 4, barrier every 2 tc.
__global__ __launch_bounds__(1024) void convspe_mfma(
    const float* __restrict__ q, const float* __restrict__ kmat,
    const float* __restrict__ wq, const float* __restrict__ wk,
    const float* __restrict__ z, float* __restrict__ parts)
{
    __shared__ __align__(16) _Float16 zbuf[4][16 * 32 * 16];   // [ts][r][d] 16KB x4 ring
    __shared__ __align__(16) _Float16 wqs[WSEG];
    __shared__ __align__(16) _Float16 wks[WSEG];

    const int tid  = threadIdx.x;
    const int wv   = tid >> 6;
    const int ssub = __builtin_amdgcn_readfirstlane(wv & 7);   // s-subtile
    const int half = __builtin_amdgcn_readfirstlane(wv >> 3);  // ts parity class
    const int lane = tid & 63;
    const int rl   = lane & 31;
    const int hi   = lane >> 5;

    const int bx = blockIdx.x;
    const int dc = bx & 3, stile = (bx >> 2) & 3, h = (bx >> 4) & 7, b = bx >> 7;
    const int s0b = stile * MS;
    const int d0  = dc * DC;

    // z staging over 1024 threads: thread = (sr, sdp d-pair, sth t-quad)
    const int sr  = tid >> 5;            // 0..31 (r)
    const int sdp = (tid >> 2) & 7;      // 0..7  (d-pair)
    const int sth = tid & 3;             // 0..3  (t-quad of 4)
    const float* zr0 = z + ((size_t)(b * RR + sr) * HD + h * DD + d0 + 2 * sdp) * ZLEN
                         + KK + s0b + sth * 4;
    const float* zr1 = zr0 + ZLEN;

    float4 ra0, rb0, ra1, rb1;           // two named prefetch sets (static indexing)
    auto loadch = [&](int tc, float4& a, float4& b) {
        a = *(const float4*)(zr0 + tc * 16);
        b = *(const float4*)(zr1 + tc * 16);
    };
    auto writech = [&](int tc, const float4& a, const float4& b) {
        f16x2* dst = (f16x2*)zbuf[tc & 3];
        const float av[4] = {a.x, a.y, a.z, a.w};
        const float bv[4] = {b.x, b.y, b.z, b.w};
        #pragma unroll
        for (int e = 0; e < 4; ++e) {
            const int ts = sth * 4 + e;
            dst[(ts * 32 + sr) * 8 + sdp] =
                __builtin_bit_cast(f16x2, __builtin_amdgcn_cvt_pkrtz(av[e], bv[e]));
        }
    };

    // start the z HBM stream first
    loadch(0, ra0, rb0);

    // per-lane q/k fragments: q[s][d0+8*hi+j] (B-operand k-layout); halves duplicate
    f16x8 qf, kf;
    {
        const int s = s0b + ssub * 32 + rl;
        const size_t base = (((size_t)b * SS + s) * HH + h) * DD + d0 + 8 * hi;
        #pragma unroll
        for (int j = 0; j < 8; ++j) {
            qf[j] = (_Float16)q[base + j];
            kf[j] = (_Float16)kmat[base + j];
        }
    }

    // folded w-prep: tid<512 -> wq table, tid>=512 -> wk table (linear [ti][di] layout)
    {
        const int t2 = tid & 511;
        const int di = t2 & 15, tq = t2 >> 4;                   // tq 0..31
        const float* warr = (tid < 512) ? wq : wk;
        _Float16* wdst    = (tid < 512) ? wqs : wks;
        const float4 v4 = *(const float4*)&warr[(h * DD + dc * DC + di) * KK + tq * 4];
        const float av[4] = {v4.x, v4.y, v4.z, v4.w};
        #pragma unroll
        for (int e = 0; e < 4; ++e)
            wdst[(tq * 4 + e + 32) * 16 + di] = (_Float16)av[e];  // ti in [32,160)
        wdst[t2] = (_Float16)0.f;                                  // rows [0,32)
        wdst[2560 + t2] = (_Float16)0.f;                           // rows [160,192)
    }

    f32x16 accq, acck;
    #pragma unroll
    for (int j = 0; j < 16; ++j) { accq[j] = 0.f; acck[j] = 0.f; }

    auto compute = [&](int tc) {
        const int tqbase = tc * 16 - ssub * 32;      // tau_s = tqbase + ts (wave-uniform)
        const int lo  = (tqbase < 0) ? -tqbase : 0;
        const int hi_ = (160 - tqbase < 16) ? (160 - tqbase) : 16;
        const int ps  = lo + ((lo ^ half) & 1);      // first ts of our parity
        if (ps >= hi_) return;
        const _Float16* zb = zbuf[tc & 3];
        auto zrd = [&](int ts) {
            return *(const f16x8*)&zb[(ts * 32 + rl) * 16 + 8 * hi];
        };
        auto wrd = [&](const _Float16* ws, int ts) {
            const int row = tqbase + ts - rl + 32;               // in [1,192)
            return *(const f16x8*)&ws[row * 16 + 8 * hi];
        };
        // 2-deep software pipeline over our parity class (ascending ts order)
        f16x8 a0 = zrd(ps), k0 = wrd(wks, ps), q0 = wrd(wqs, ps);
        f16x8 a1 = a0, k1 = k0, q1 = q0;
        if (ps + 2 < hi_) { a1 = zrd(ps + 2); k1 = wrd(wks, ps + 2); q1 = wrd(wqs, ps + 2); }
        for (int ts = ps; ts < hi_ - 4; ts += 2) {
            const f16x8 a2 = zrd(ts + 4), k2 = wrd(wks, ts + 4), q2 = wrd(wqs, ts + 4);
            accq = __builtin_amdgcn_mfma_f32_32x32x16_f16(a0, k0 * qf, accq, 0, 0, 0); // qbar uses wk
            acck = __builtin_amdgcn_mfma_f32_32x32x16_f16(a0, q0 * kf, acck, 0, 0, 0); // kbar uses wq
            a0 = a1; k0 = k1; q0 = q1;
            a1 = a2; k1 = k2; q1 = q2;
        }
        accq = __builtin_amdgcn_mfma_f32_32x32x16_f16(a0, k0 * qf, accq, 0, 0, 0);
        acck = __builtin_amdgcn_mfma_f32_32x32x16_f16(a0, q0 * kf, acck, 0, 0, 0);
        if (ps + 2 < hi_) {
            accq = __builtin_amdgcn_mfma_f32_32x32x16_f16(a1, k1 * qf, accq, 0, 0, 0);
            acck = __builtin_amdgcn_mfma_f32_32x32x16_f16(a1, q1 * kf, acck, 0, 0, 0);
        }
    };

    // prologue: buffers 0,1 staged; loads for 2,3 in flight
    loadch(1, ra1, rb1);
    writech(0, ra0, rb0);
    loadch(2, ra0, rb0);
    writech(1, ra1, rb1);
    loadch(3, ra1, rb1);
    __syncthreads();     // zbuf0/1 + w tables ready

    // main: segments of 2 tc, one barrier per segment.
    // writech lead 2 (into ring slots read next segment); loadch lead 4.
    for (int t2 = 0; t2 < NTC; t2 += 2) {
        if (t2 + 2 < NTC) writech(t2 + 2, ra0, rb0);
        if (t2 + 4 < NTC) loadch(t2 + 4, ra0, rb0);
        compute(t2);
        if (t2 + 3 < NTC) writech(t2 + 3, ra1, rb1);
        if (t2 + 5 < NTC) loadch(t2 + 5, ra1, rb1);
        compute(t2 + 1);
        __syncthreads();
    }

    // ---- in-block parity merge via LDS (reuse zbuf: 8192 f32, conflict-free columns) ----
    {
        float* mrg = (float*)zbuf;
        const int col = ssub * 64 + lane;            // 0..511
        if (half == 1) {
            #pragma unroll
            for (int j = 0; j < 16; ++j) mrg[j * 512 + col] = accq[j];
        }
        __syncthreads();
        if (half == 0) {
            #pragma unroll
            for (int j = 0; j < 16; ++j) accq[j] += mrg[j * 512 + col];
        }
        __syncthreads();
        if (half == 1) {
            #pragma unroll
            for (int j = 0; j < 16; ++j) mrg[j * 512 + col] = acck[j];
        }
        __syncthreads();
        if (half == 0) {
            #pragma unroll
            for (int j = 0; j < 16; ++j) acck[j] += mrg[j * 512 + col];
        }
    }

    // partials: parts[bx][sub][o][lane][reg]  (half==0 waves only; layout unchanged)
    if (half == 0) {
        float* pq = parts + ((((size_t)bx * 8 + ssub) * 2 + 0) * 64 + lane) * 16;
        float* pk = parts + ((((size_t)bx * 8 + ssub) * 2 + 1) * 64 + lane) * 16;
        #pragma unroll
        for (int g = 0; g < 4; ++g) {
            *(float4*)&pq[g * 4] = make_float4(accq[4*g], accq[4*g+1], accq[4*g+2], accq[4*g+3]);
            *(float4*)&pk[g * 4] = make_float4(acck[4*g], acck[4*g+1], acck[4*g+2], acck[4*g+3]);
        }
    }
}

// ---- reduce over dc: out[o][b][s][h][r], thread = one r-quad (float4 in, float4 out) ----
__global__ __launch_bounds__(256) void reduce_kernel(
    const float* __restrict__ parts, float* __restrict__ out)
{
    const int idx = blockIdx.x * 256 + threadIdx.x;   // 0..262143
    const int rq = idx & 7, h = (idx >> 3) & 7, s = (idx >> 6) & 1023;
    const int b = (idx >> 16) & 1, o = idx >> 17;
    const int stile = s >> 8, sub = (s >> 5) & 7, rl = s & 31;

    // r = rq*4+i: hi2 = rq&1, reg = i + 4*(rq>>1)  ->  4 consecutive floats
    const int off = ((rq & 1) * 32 + rl) * 16 + 4 * (rq >> 1);

    float4 acc = make_float4(0.f, 0.f, 0.f, 0.f);
    #pragma unroll
    for (int dc = 0; dc < 4; ++dc) {
        const int bx = ((b * 8 + h) * 4 + stile) * 4 + dc;
        const float4 v = *(const float4*)&parts[(((size_t)bx * 8 + sub) * 2 + o) * 1024 + off];
        acc.x += v.x; acc.y += v.y; acc.z += v.z; acc.w += v.w;
    }
    *(float4*)&out[(size_t)idx * 4] = acc;
}

extern "C" void kernel_launch(void* const* d_in, const int* in_sizes, int n_in,
                              void* d_out, int out_size, void* d_ws, size_t ws_size,
                              hipStream_t stream) {
    const float* q  = (const float*)d_in[0];
    const float* k  = (const float*)d_in[1];
    const float* wq = (const float*)d_in[2];
    const float* wk = (const float*)d_in[3];
    const float* z  = (const float*)d_in[4];
    float* out = (float*)d_out;

    float* parts = (float*)d_ws;                                 // 16 MiB

    hipLaunchKernelGGL(convspe_mfma, dim3(256), dim3(1024), 0, stream,
                       q, k, wq, wk, z, parts);
    hipLaunchKernelGGL(reduce_kernel, dim3(1024), dim3(256), 0, stream, parts, out);
}

// Round 5
// 299.365 us; speedup vs baseline: 1.0141x; 1.0141x over previous
//
#include <hip/hip_runtime.h>

// dims
#define BB 2
#define SS 1024
#define HH 8
#define DD 64
#define RR 32
#define KK 128
#define ZLEN 1536
#define HD 512

// tiling
#define MS 256            // s per block (4 stiles)
#define DC 16             // d per block (4 dc chunks)
#define NTC 24            // t-chunks of 16 (window = 256+128 = 384)
#define WROWS 192         // tau in [-32,160), zero-padded outside [0,128)
#define WSEG (WROWS*DC)   // 3072 halves = 6 KB per (h,dc) per array
#define PARTS_FLOATS (256*8*2*64*16)   // 4,194,304 f32 = 16 MiB

typedef _Float16 f16x8 __attribute__((ext_vector_type(8)));
typedef _Float16 f16x2 __attribute__((ext_vector_type(2)));
typedef float    f32x16 __attribute__((ext_vector_type(16)));

// ---- main: C[r][s] = sum_{t,d} z[r,d,t] * (w[d,t-s]*qk[s,d]), MFMA 32x32x16 f16 ----
// block = (b,h,stile,dc), 1024 thr = 16 waves: wave = (ssub 0..7, parity half).
// 4-deep zbuf ring, write-lead 2, global-load lead 4, barrier every 2 tc.
// NEW: serpentine t-order (odd stiles descend) + XCD co-location so the
// 128-t overlap between adjacent stiles is read co-timed -> L2/LLC hit.
__global__ __launch_bounds__(1024) void convspe_mfma(
    const float* __restrict__ q, const float* __restrict__ kmat,
    const float* __restrict__ wq, const float* __restrict__ wk,
    const float* __restrict__ z, float* __restrict__ parts)
{
    __shared__ __align__(16) _Float16 zbuf[4][16 * 32 * 16];   // [ts][r][d] 16KB x4 ring
    __shared__ __align__(16) _Float16 wqs[WSEG];
    __shared__ __align__(16) _Float16 wks[WSEG];

    const int tid  = threadIdx.x;
    const int wv   = tid >> 6;
    const int ssub = __builtin_amdgcn_readfirstlane(wv & 7);   // s-subtile
    const int half = __builtin_amdgcn_readfirstlane(wv >> 3);  // ts parity class
    const int lane = tid & 63;
    const int rl   = lane & 31;
    const int hi   = lane >> 5;

    // physical bx -> logical (b,h,stile,dc): all 16 blocks of one (b,h) land on
    // one XCD (assumes round-robin bx%8 -> XCD; wrong mapping only costs perf).
    const int bx   = blockIdx.x;
    const int xcd  = bx & 7, slot = bx >> 3;
    const int g    = xcd * 2 + (slot & 1);        // (b,h) group 0..15
    const int i16  = slot >> 1;                   // 0..15 within group
    const int b    = g >> 3, h = g & 7;
    const int stile = i16 >> 2, dc = i16 & 3;
    const int lbx  = ((b * 8 + h) * 4 + stile) * 4 + dc;   // logical index for parts
    const int dir  = stile & 1;                   // odd stiles run t descending
    const int s0b  = stile * MS;
    const int d0   = dc * DC;

    auto M = [&](int i) { return dir ? (NTC - 1 - i) : i; };

    // z staging over 1024 threads: thread = (sr, sdp d-pair, sth t-quad)
    const int sr  = tid >> 5;            // 0..31 (r)
    const int sdp = (tid >> 2) & 7;      // 0..7  (d-pair)
    const int sth = tid & 3;             // 0..3  (t-quad of 4)
    const float* zr0 = z + ((size_t)(b * RR + sr) * HD + h * DD + d0 + 2 * sdp) * ZLEN
                         + KK + s0b + sth * 4;
    const float* zr1 = zr0 + ZLEN;

    float4 ra0, rb0, ra1, rb1;           // two named prefetch sets (static indexing)
    auto loadch = [&](int tc, float4& a, float4& b_) {
        a  = *(const float4*)(zr0 + tc * 16);
        b_ = *(const float4*)(zr1 + tc * 16);
    };
    auto writech = [&](int tc, const float4& a, const float4& b_) {
        f16x2* dst = (f16x2*)zbuf[tc & 3];
        const float av[4] = {a.x, a.y, a.z, a.w};
        const float bv[4] = {b_.x, b_.y, b_.z, b_.w};
        #pragma unroll
        for (int e = 0; e < 4; ++e) {
            const int ts = sth * 4 + e;
            dst[(ts * 32 + sr) * 8 + sdp] =
                __builtin_bit_cast(f16x2, __builtin_amdgcn_cvt_pkrtz(av[e], bv[e]));
        }
    };

    // start the z HBM stream first
    loadch(M(0), ra0, rb0);

    // per-lane q/k fragments: q[s][d0+8*hi+j] (B-operand k-layout); halves duplicate
    f16x8 qf, kf;
    {
        const int s = s0b + ssub * 32 + rl;
        const size_t base = (((size_t)b * SS + s) * HH + h) * DD + d0 + 8 * hi;
        #pragma unroll
        for (int j = 0; j < 8; ++j) {
            qf[j] = (_Float16)q[base + j];
            kf[j] = (_Float16)kmat[base + j];
        }
    }

    // folded w-prep: tid<512 -> wq table, tid>=512 -> wk table (linear [ti][di] layout)
    {
        const int t2 = tid & 511;
        const int di = t2 & 15, tq = t2 >> 4;                   // tq 0..31
        const float* warr = (tid < 512) ? wq : wk;
        _Float16* wdst    = (tid < 512) ? wqs : wks;
        const float4 v4 = *(const float4*)&warr[(h * DD + dc * DC + di) * KK + tq * 4];
        const float av[4] = {v4.x, v4.y, v4.z, v4.w};
        #pragma unroll
        for (int e = 0; e < 4; ++e)
            wdst[(tq * 4 + e + 32) * 16 + di] = (_Float16)av[e];  // ti in [32,160)
        wdst[t2] = (_Float16)0.f;                                  // rows [0,32)
        wdst[2560 + t2] = (_Float16)0.f;                           // rows [160,192)
    }

    f32x16 accq, acck;
    #pragma unroll
    for (int j = 0; j < 16; ++j) { accq[j] = 0.f; acck[j] = 0.f; }

    auto compute = [&](int tc) {
        const int tqbase = tc * 16 - ssub * 32;      // tau_s = tqbase + ts (wave-uniform)
        const int lo  = (tqbase < 0) ? -tqbase : 0;
        const int hi_ = (160 - tqbase < 16) ? (160 - tqbase) : 16;
        const int ps  = lo + ((lo ^ half) & 1);      // first ts of our parity
        if (ps >= hi_) return;
        const _Float16* zb = zbuf[tc & 3];
        auto zrd = [&](int ts) {
            return *(const f16x8*)&zb[(ts * 32 + rl) * 16 + 8 * hi];
        };
        auto wrd = [&](const _Float16* ws, int ts) {
            const int row = tqbase + ts - rl + 32;               // in [1,192)
            return *(const f16x8*)&ws[row * 16 + 8 * hi];
        };
        // 2-deep software pipeline over our parity class (ascending ts order)
        f16x8 a0 = zrd(ps), k0 = wrd(wks, ps), q0 = wrd(wqs, ps);
        f16x8 a1 = a0, k1 = k0, q1 = q0;
        if (ps + 2 < hi_) { a1 = zrd(ps + 2); k1 = wrd(wks, ps + 2); q1 = wrd(wqs, ps + 2); }
        for (int ts = ps; ts < hi_ - 4; ts += 2) {
            const f16x8 a2 = zrd(ts + 4), k2 = wrd(wks, ts + 4), q2 = wrd(wqs, ts + 4);
            accq = __builtin_amdgcn_mfma_f32_32x32x16_f16(a0, k0 * qf, accq, 0, 0, 0); // qbar uses wk
            acck = __builtin_amdgcn_mfma_f32_32x32x16_f16(a0, q0 * kf, acck, 0, 0, 0); // kbar uses wq
            a0 = a1; k0 = k1; q0 = q1;
            a1 = a2; k1 = k2; q1 = q2;
        }
        accq = __builtin_amdgcn_mfma_f32_32x32x16_f16(a0, k0 * qf, accq, 0, 0, 0);
        acck = __builtin_amdgcn_mfma_f32_32x32x16_f16(a0, q0 * kf, acck, 0, 0, 0);
        if (ps + 2 < hi_) {
            accq = __builtin_amdgcn_mfma_f32_32x32x16_f16(a1, k1 * qf, accq, 0, 0, 0);
            acck = __builtin_amdgcn_mfma_f32_32x32x16_f16(a1, q1 * kf, acck, 0, 0, 0);
        }
    };

    // prologue: buffers for i=0,1 staged; loads for i=2,3 in flight
    loadch(M(1), ra1, rb1);
    writech(M(0), ra0, rb0);
    loadch(M(2), ra0, rb0);
    writech(M(1), ra1, rb1);
    loadch(M(3), ra1, rb1);
    __syncthreads();     // first two buffers + w tables ready

    // main: segments of 2 iters, one barrier per segment.
    // writech lead 2 (into ring slots read next segment); loadch lead 4.
    for (int i2 = 0; i2 < NTC; i2 += 2) {
        if (i2 + 2 < NTC) writech(M(i2 + 2), ra0, rb0);
        if (i2 + 4 < NTC) loadch(M(i2 + 4), ra0, rb0);
        compute(M(i2));
        if (i2 + 3 < NTC) writech(M(i2 + 3), ra1, rb1);
        if (i2 + 5 < NTC) loadch(M(i2 + 5), ra1, rb1);
        compute(M(i2 + 1));
        __syncthreads();
    }

    // ---- in-block parity merge via LDS (reuse zbuf: 8192 f32, conflict-free columns) ----
    {
        float* mrg = (float*)zbuf;
        const int col = ssub * 64 + lane;            // 0..511
        if (half == 1) {
            #pragma unroll
            for (int j = 0; j < 16; ++j) mrg[j * 512 + col] = accq[j];
        }
        __syncthreads();
        if (half == 0) {
            #pragma unroll
            for (int j = 0; j < 16; ++j) accq[j] += mrg[j * 512 + col];
        }
        __syncthreads();
        if (half == 1) {
            #pragma unroll
            for (int j = 0; j < 16; ++j) mrg[j * 512 + col] = acck[j];
        }
        __syncthreads();
        if (half == 0) {
            #pragma unroll
            for (int j = 0; j < 16; ++j) acck[j] += mrg[j * 512 + col];
        }
    }

    // partials: parts[lbx][sub][o][lane][reg]  (half==0 waves only; layout unchanged)
    if (half == 0) {
        float* pq = parts + ((((size_t)lbx * 8 + ssub) * 2 + 0) * 64 + lane) * 16;
        float* pk = parts + ((((size_t)lbx * 8 + ssub) * 2 + 1) * 64 + lane) * 16;
        #pragma unroll
        for (int g2 = 0; g2 < 4; ++g2) {
            *(float4*)&pq[g2 * 4] = make_float4(accq[4*g2], accq[4*g2+1], accq[4*g2+2], accq[4*g2+3]);
            *(float4*)&pk[g2 * 4] = make_float4(acck[4*g2], acck[4*g2+1], acck[4*g2+2], acck[4*g2+3]);
        }
    }
}

// ---- reduce over dc: out[o][b][s][h][r], thread = one r-quad (float4 in, float4 out) ----
__global__ __launch_bounds__(256) void reduce_kernel(
    const float* __restrict__ parts, float* __restrict__ out)
{
    const int idx = blockIdx.x * 256 + threadIdx.x;   // 0..262143
    const int rq = idx & 7, h = (idx >> 3) & 7, s = (idx >> 6) & 1023;
    const int b = (idx >> 16) & 1, o = idx >> 17;
    const int stile = s >> 8, sub = (s >> 5) & 7, rl = s & 31;

    // r = rq*4+i: hi2 = rq&1, reg = i + 4*(rq>>1)  ->  4 consecutive floats
    const int off = ((rq & 1) * 32 + rl) * 16 + 4 * (rq >> 1);

    float4 acc = make_float4(0.f, 0.f, 0.f, 0.f);
    #pragma unroll
    for (int dc = 0; dc < 4; ++dc) {
        const int bx = ((b * 8 + h) * 4 + stile) * 4 + dc;
        const float4 v = *(const float4*)&parts[(((size_t)bx * 8 + sub) * 2 + o) * 1024 + off];
        acc.x += v.x; acc.y += v.y; acc.z += v.z; acc.w += v.w;
    }
    *(float4*)&out[(size_t)idx * 4] = acc;
}

extern "C" void kernel_launch(void* const* d_in, const int* in_sizes, int n_in,
                              void* d_out, int out_size, void* d_ws, size_t ws_size,
                              hipStream_t stream) {
    const float* q  = (const float*)d_in[0];
    const float* k  = (const float*)d_in[1];
    const float* wq = (const float*)d_in[2];
    const float* wk = (const float*)d_in[3];
    const float* z  = (const float*)d_in[4];
    float* out = (float*)d_out;

    float* parts = (float*)d_ws;                                 // 16 MiB

    hipLaunchKernelGGL(convspe_mfma, dim3(256), dim3(1024), 0, stream,
                       q, k, wq, wk, z, parts);
    hipLaunchKernelGGL(reduce_kernel, dim3(1024), dim3(256), 0, stream, parts, out);
}